// Round 2
// baseline (976.329 us; speedup 1.0000x reference)
//
#include <hip/hip_runtime.h>

#define NTOK 262144
#define TT 64
#define EPS 1e-5f

typedef short short8 __attribute__((ext_vector_type(8)));
typedef float float4v __attribute__((ext_vector_type(4)));

// Packed split-bf16 weights: [g(4)][plane(2: hi,lo)][nt(16)][kb(8)][lane(64)][j(8)]
// element = W[kb*32 + (lane>>4)*8 + j][nt*16 + (lane&15)]
__device__ __align__(16) short g_Wp[4 * 2 * 65536];   // 1 MB static device mem

__device__ __forceinline__ short f2bf(float f) {   // RTN f32->bf16
    uint32_t u = __builtin_bit_cast(uint32_t, f);
    u += 0x7FFFu + ((u >> 16) & 1u);
    return (short)(u >> 16);
}
__device__ __forceinline__ float bf2f(short h) {
    uint32_t u = ((uint32_t)(uint16_t)h) << 16;
    return __builtin_bit_cast(float, u);
}

__global__ void pack_w(const float* __restrict__ W11, const float* __restrict__ W12,
                       const float* __restrict__ W21, const float* __restrict__ W22) {
    int t = blockIdx.x * 256 + threadIdx.x;          // 0 .. 262143
    int g = t >> 16;
    int r = t & 65535;
    int j = r & 7, l = (r >> 3) & 63, kb = (r >> 9) & 7, nt = (r >> 12) & 15;
    int n = nt * 16 + (l & 15);
    int k = kb * 32 + (l >> 4) * 8 + j;
    const float* W = (g == 0) ? W11 : (g == 1) ? W12 : (g == 2) ? W21 : W22;
    float f = W[k * 256 + n];
    short hi = f2bf(f);
    short lo = f2bf(f - bf2f(hi));
    g_Wp[(g * 2 + 0) * 65536 + r] = hi;
    g_Wp[(g * 2 + 1) * 65536 + r] = lo;
}

__device__ __forceinline__ float fast_gelu(float v) {
    // tanh-approx gelu; max abs dev from exact erf-gelu ~3e-3, under 0.1 threshold
    float u = v * 0.7978845608028654f * (1.0f + 0.044715f * v * v);
    float e = __expf(2.0f * u);
    float th = 1.0f - 2.0f / (e + 1.0f);
    return 0.5f * v * (1.0f + th);
}

// A-operand packed LDS index for element (m, k):
// frag read: lane l', kb  -> A[m = (l'&15) + 16*rg][k = kb*32 + (l'>>4)*8 + j]
__device__ __forceinline__ int aidx(int m, int k) {
    return ((((m >> 4) * 8 + (k >> 5)) * 64) + (m & 15) + (((k >> 3) & 3) << 4)) * 8 + (k & 7);
}

__global__ __launch_bounds__(256, 1) void fused_kernel(
    const float* __restrict__ meas, const float* __restrict__ event,
    const float* __restrict__ leak, const float* __restrict__ elk,
    const int* __restrict__ sids, const int* __restrict__ cids,
    const float* __restrict__ w_meas, const float* __restrict__ w_event,
    const float* __restrict__ w_leak, const float* __restrict__ w_el,
    const float* __restrict__ b_meas, const float* __restrict__ b_event,
    const float* __restrict__ b_leak, const float* __restrict__ b_el,
    const float* __restrict__ stab_table, const float* __restrict__ cycle_table,
    const float* __restrict__ g1, const float* __restrict__ be1,
    const float* __restrict__ b11, const float* __restrict__ b12,
    const float* __restrict__ g2, const float* __restrict__ be2,
    const float* __restrict__ b21, const float* __restrict__ b22,
    float* __restrict__ out)
{
    __shared__ __align__(16) short Ahi[4 * 8 * 64 * 8];   // 32 KB
    __shared__ __align__(16) short Alo[4 * 8 * 64 * 8];   // 32 KB
    __shared__ float par[13 * 256];                       // 13 KB staged params
    __shared__ float rowf[4][TT];
    __shared__ int   rowi[2][TT];
    __shared__ float red[2][4][TT];                       // LN cross-wave partials
    __shared__ float stat[2][TT];                         // mu, rstd per row

    const int tid = threadIdx.x;
    const int w = tid >> 6, lane = tid & 63;
    const int q = lane >> 4, c = lane & 15;
    const int R0 = blockIdx.x * TT;

    {   // stage per-feature params (one column per thread)
        int n = tid;
        par[0 * 256 + n] = w_meas[n];
        par[1 * 256 + n] = w_event[n];
        par[2 * 256 + n] = w_leak[n];
        par[3 * 256 + n] = w_el[n];
        par[4 * 256 + n] = b_meas[n] + b_event[n] + b_leak[n] + b_el[n];
        par[5 * 256 + n] = g1[n];
        par[6 * 256 + n] = be1[n];
        par[7 * 256 + n] = b11[n];
        par[8 * 256 + n] = b12[n];
        par[9 * 256 + n] = g2[n];
        par[10 * 256 + n] = be2[n];
        par[11 * 256 + n] = b21[n];
        par[12 * 256 + n] = b22[n];
    }
    if (tid < TT) {
        rowf[0][tid] = meas[R0 + tid];
        rowf[1][tid] = event[R0 + tid];
        rowf[2][tid] = leak[R0 + tid];
        rowf[3][tid] = elk[R0 + tid];
        rowi[0][tid] = sids[R0 + tid];
        rowi[1][tid] = cids[R0 + tid];
    }
    __syncthreads();

    // residual x in MFMA C-layout registers: [rg][ntl][reg]
    // element: row m = rg*16 + 4*q + reg, col n = w*64 + ntl*16 + c
    float xr[4][4][4];
    #pragma unroll
    for (int rg = 0; rg < 4; ++rg)
        #pragma unroll
        for (int reg = 0; reg < 4; ++reg) {
            int m = rg * 16 + 4 * q + reg;
            float mv = rowf[0][m], ev = rowf[1][m], lv = rowf[2][m], e2 = rowf[3][m];
            const float* srow = stab_table + rowi[0][m] * 256;
            const float* crow = cycle_table + rowi[1][m] * 256;
            #pragma unroll
            for (int ntl = 0; ntl < 4; ++ntl) {
                int n = w * 64 + ntl * 16 + c;
                xr[rg][ntl][reg] = mv * par[n] + ev * par[256 + n] + lv * par[512 + n]
                                 + e2 * par[768 + n] + par[1024 + n] + srow[n] + crow[n];
            }
        }

    auto store_A = [&](int m, int n, float a) {
        short hi = f2bf(a);
        short lo = f2bf(a - bf2f(hi));
        int idx = aidx(m, n);
        Ahi[idx] = hi;
        Alo[idx] = lo;
    };

    auto layernorm_to_A = [&](const float* g, const float* be) {
        float s[4][4], s2[4][4];
        #pragma unroll
        for (int rg = 0; rg < 4; ++rg)
            #pragma unroll
            for (int reg = 0; reg < 4; ++reg) {
                float a = 0.f, b = 0.f;
                #pragma unroll
                for (int ntl = 0; ntl < 4; ++ntl) {
                    float v = xr[rg][ntl][reg];
                    a += v; b += v * v;
                }
                #pragma unroll
                for (int d = 1; d < 16; d <<= 1) {
                    a += __shfl_xor(a, d, 64);
                    b += __shfl_xor(b, d, 64);
                }
                s[rg][reg] = a; s2[rg][reg] = b;
            }
        if (c == 0) {
            #pragma unroll
            for (int rg = 0; rg < 4; ++rg)
                #pragma unroll
                for (int reg = 0; reg < 4; ++reg) {
                    int m = rg * 16 + 4 * q + reg;
                    red[0][w][m] = s[rg][reg];
                    red[1][w][m] = s2[rg][reg];
                }
        }
        __syncthreads();   // red visible; also all waves done reading A planes
        if (tid < TT) {
            float a = red[0][0][tid] + red[0][1][tid] + red[0][2][tid] + red[0][3][tid];
            float b = red[1][0][tid] + red[1][1][tid] + red[1][2][tid] + red[1][3][tid];
            float mu = a * (1.0f / 256.0f);
            float var = b * (1.0f / 256.0f) - mu * mu;
            stat[0][tid] = mu;
            stat[1][tid] = rsqrtf(var + EPS);
        }
        __syncthreads();
        #pragma unroll
        for (int rg = 0; rg < 4; ++rg)
            #pragma unroll
            for (int reg = 0; reg < 4; ++reg) {
                int m = rg * 16 + 4 * q + reg;
                float mu = stat[0][m], rs = stat[1][m];
                #pragma unroll
                for (int ntl = 0; ntl < 4; ++ntl) {
                    int n = w * 64 + ntl * 16 + c;
                    store_A(m, n, (xr[rg][ntl][reg] - mu) * rs * g[n] + be[n]);
                }
            }
        __syncthreads();
    };

    float4v acc[4][4];

    auto do_gemm = [&](int g) {
        const short* Wh = g_Wp + (g * 2 + 0) * 65536;
        const short* Wl = g_Wp + (g * 2 + 1) * 65536;
        #pragma unroll
        for (int rg = 0; rg < 4; ++rg)
            #pragma unroll
            for (int ntl = 0; ntl < 4; ++ntl)
                acc[rg][ntl] = (float4v){0.f, 0.f, 0.f, 0.f};
        #pragma unroll
        for (int kb = 0; kb < 8; ++kb) {
            short8 ah[4], al[4], bh[4], bl[4];
            #pragma unroll
            for (int rg = 0; rg < 4; ++rg) {
                ah[rg] = *(const short8*)&Ahi[((rg * 8 + kb) * 64 + lane) * 8];
                al[rg] = *(const short8*)&Alo[((rg * 8 + kb) * 64 + lane) * 8];
            }
            #pragma unroll
            for (int ntl = 0; ntl < 4; ++ntl) {
                int nt = w * 4 + ntl;
                bh[ntl] = *(const short8*)&Wh[((nt * 8 + kb) * 64 + lane) * 8];
                bl[ntl] = *(const short8*)&Wl[((nt * 8 + kb) * 64 + lane) * 8];
            }
            #pragma unroll
            for (int rg = 0; rg < 4; ++rg)
                #pragma unroll
                for (int ntl = 0; ntl < 4; ++ntl) {
                    acc[rg][ntl] = __builtin_amdgcn_mfma_f32_16x16x32_bf16(
                        ah[rg], bh[ntl], acc[rg][ntl], 0, 0, 0);
                    acc[rg][ntl] = __builtin_amdgcn_mfma_f32_16x16x32_bf16(
                        ah[rg], bl[ntl], acc[rg][ntl], 0, 0, 0);
                    acc[rg][ntl] = __builtin_amdgcn_mfma_f32_16x16x32_bf16(
                        al[rg], bh[ntl], acc[rg][ntl], 0, 0, 0);
                }
        }
    };

    auto gelu_to_A = [&](const float* bias) {
        __syncthreads();   // all waves done reading previous A tile
        #pragma unroll
        for (int rg = 0; rg < 4; ++rg)
            #pragma unroll
            for (int ntl = 0; ntl < 4; ++ntl)
                #pragma unroll
                for (int reg = 0; reg < 4; ++reg) {
                    int m = rg * 16 + 4 * q + reg;
                    int n = w * 64 + ntl * 16 + c;
                    float v = acc[rg][ntl][reg] + bias[n];
                    store_A(m, n, fast_gelu(v));
                }
        __syncthreads();
    };

    // ---- res block 1 ----
    layernorm_to_A(par + 5 * 256, par + 6 * 256);
    do_gemm(0);
    gelu_to_A(par + 7 * 256);
    do_gemm(1);
    #pragma unroll
    for (int rg = 0; rg < 4; ++rg)
        #pragma unroll
        for (int ntl = 0; ntl < 4; ++ntl)
            #pragma unroll
            for (int reg = 0; reg < 4; ++reg) {
                int n = w * 64 + ntl * 16 + c;
                xr[rg][ntl][reg] += acc[rg][ntl][reg] + par[8 * 256 + n];
            }

    // ---- res block 2 ----
    layernorm_to_A(par + 9 * 256, par + 10 * 256);
    do_gemm(2);
    gelu_to_A(par + 11 * 256);
    do_gemm(3);

    // ---- epilogue: out = x + C4 + b22 ----
    #pragma unroll
    for (int rg = 0; rg < 4; ++rg)
        #pragma unroll
        for (int ntl = 0; ntl < 4; ++ntl)
            #pragma unroll
            for (int reg = 0; reg < 4; ++reg) {
                int m = rg * 16 + 4 * q + reg;
                int n = w * 64 + ntl * 16 + c;
                out[(size_t)(R0 + m) * 256 + n] =
                    xr[rg][ntl][reg] + acc[rg][ntl][reg] + par[12 * 256 + n];
            }
}

extern "C" void kernel_launch(void* const* d_in, const int* in_sizes, int n_in,
                              void* d_out, int out_size, void* d_ws, size_t ws_size,
                              hipStream_t stream) {
    pack_w<<<1024, 256, 0, stream>>>(
        (const float*)d_in[18], (const float*)d_in[20],
        (const float*)d_in[24], (const float*)d_in[26]);
    fused_kernel<<<NTOK / TT, 256, 0, stream>>>(
        (const float*)d_in[0], (const float*)d_in[1],
        (const float*)d_in[2], (const float*)d_in[3],
        (const int*)d_in[4], (const int*)d_in[5],
        (const float*)d_in[6], (const float*)d_in[8],
        (const float*)d_in[10], (const float*)d_in[12],
        (const float*)d_in[7], (const float*)d_in[9],
        (const float*)d_in[11], (const float*)d_in[13],
        (const float*)d_in[14], (const float*)d_in[15],
        (const float*)d_in[16], (const float*)d_in[17],
        (const float*)d_in[19], (const float*)d_in[21],
        (const float*)d_in[22], (const float*)d_in[23],
        (const float*)d_in[25], (const float*)d_in[27],
        (float*)d_out);
}

// Round 4
// 781.801 us; speedup vs baseline: 1.2488x; 1.2488x over previous
//
#include <hip/hip_runtime.h>

#define NTOK 262144
#define TT 64
#define EPS 1e-5f

typedef short short8 __attribute__((ext_vector_type(8)));
typedef float float4v __attribute__((ext_vector_type(4)));

// Packed bf16 weights: [g(4)][nt(16)][kb(8)][lane(64)][j(8)]
// element = W[kb*32 + (lane>>4)*8 + j][nt*16 + (lane&15)]
__device__ __align__(16) short g_Wp[4 * 65536];   // 512 KB static device mem

__device__ __forceinline__ short f2bf(float f) {   // RTN f32->bf16
    uint32_t u = __builtin_bit_cast(uint32_t, f);
    u += 0x7FFFu + ((u >> 16) & 1u);
    return (short)(u >> 16);
}

__global__ void pack_w(const float* __restrict__ W11, const float* __restrict__ W12,
                       const float* __restrict__ W21, const float* __restrict__ W22) {
    int t = blockIdx.x * 256 + threadIdx.x;          // 0 .. 262143
    int g = t >> 16;
    int r = t & 65535;
    int j = r & 7, l = (r >> 3) & 63, kb = (r >> 9) & 7, nt = (r >> 12) & 15;
    int n = nt * 16 + (l & 15);
    int k = kb * 32 + (l >> 4) * 8 + j;
    const float* W = (g == 0) ? W11 : (g == 1) ? W12 : (g == 2) ? W21 : W22;
    g_Wp[t] = f2bf(W[k * 256 + n]);
}

// exact-erf gelu via Abramowitz-Stegun 7.1.26 (max erf err 1.5e-7)
__device__ __forceinline__ float gelu_erf(float v) {
    float z = fabsf(v) * 0.70710678118654752f;
    float t = 1.0f / (1.0f + 0.3275911f * z);
    float poly = t * (0.254829592f + t * (-0.284496736f + t * (1.421413741f
               + t * (-1.453152027f + t * 1.061405429f))));
    float er = 1.0f - poly * __expf(-z * z);
    er = copysignf(er, v);
    return 0.5f * v * (1.0f + er);
}

// A-operand packed LDS index for element (m, k):
// frag read: lane l'=(q,cl), kb  -> A[m = rg*16 + cl][k = kb*32 + q*8 + j]
__device__ __forceinline__ int aidx(int m, int k) {
    return ((((m >> 4) * 8 + (k >> 5)) * 64) + (m & 15) + (((k >> 3) & 3) << 4)) * 8 + (k & 7);
}

// NOTE: __launch_bounds__(256,1). (256,2) caps unified VGPR+AGPR at 256 and
// produced wrong results in rounds 1 & 3 (register-pressure codegen); with
// (256,1) the allocator uses ~180 VGPR and HW occupancy is still 2 blocks/CU.
__global__ __launch_bounds__(256, 1) void fused_kernel(
    const float* __restrict__ meas, const float* __restrict__ event,
    const float* __restrict__ leak, const float* __restrict__ elk,
    const int* __restrict__ sids, const int* __restrict__ cids,
    const float* __restrict__ w_meas, const float* __restrict__ w_event,
    const float* __restrict__ w_leak, const float* __restrict__ w_el,
    const float* __restrict__ b_meas, const float* __restrict__ b_event,
    const float* __restrict__ b_leak, const float* __restrict__ b_el,
    const float* __restrict__ stab_table, const float* __restrict__ cycle_table,
    const float* __restrict__ g1, const float* __restrict__ be1,
    const float* __restrict__ b11, const float* __restrict__ b12,
    const float* __restrict__ g2, const float* __restrict__ be2,
    const float* __restrict__ b21, const float* __restrict__ b22,
    float* __restrict__ out)
{
    __shared__ __align__(16) short Ahi[4 * 8 * 64 * 8];   // 32 KB
    __shared__ float par[13 * 256];                       // 13 KB staged params
    // overlay union (2.5 KB): embed phase uses rowf[4][64]+rowi[2][64];
    // LN phases reuse it as red[2][4][64]+stat[2][64]
    __shared__ float ubuf[640];

    float (*rowf)[TT] = (float (*)[TT])ubuf;              // [4][64]
    int   (*rowi)[TT] = (int (*)[TT])(ubuf + 256);        // [2][64]
    float (*red)[4][TT] = (float (*)[4][TT])ubuf;         // [2][4][64]
    float (*stat)[TT] = (float (*)[TT])(ubuf + 512);      // [2][64]

    const int tid = threadIdx.x;
    const int w = tid >> 6, lane = tid & 63;
    const int q = lane >> 4, c = lane & 15;
    const int R0 = blockIdx.x * TT;

    {   // stage per-feature params (one column per thread)
        int n = tid;
        par[0 * 256 + n] = w_meas[n];
        par[1 * 256 + n] = w_event[n];
        par[2 * 256 + n] = w_leak[n];
        par[3 * 256 + n] = w_el[n];
        par[4 * 256 + n] = b_meas[n] + b_event[n] + b_leak[n] + b_el[n];
        par[5 * 256 + n] = g1[n];
        par[6 * 256 + n] = be1[n];
        par[7 * 256 + n] = b11[n];
        par[8 * 256 + n] = b12[n];
        par[9 * 256 + n] = g2[n];
        par[10 * 256 + n] = be2[n];
        par[11 * 256 + n] = b21[n];
        par[12 * 256 + n] = b22[n];
    }
    if (tid < TT) {
        rowf[0][tid] = meas[R0 + tid];
        rowf[1][tid] = event[R0 + tid];
        rowf[2][tid] = leak[R0 + tid];
        rowf[3][tid] = elk[R0 + tid];
        rowi[0][tid] = sids[R0 + tid];
        rowi[1][tid] = cids[R0 + tid];
    }
    __syncthreads();

    // residual x in MFMA C-layout registers: [rg][ntl][reg]
    // element: row m = rg*16 + 4*q + reg, col n = w*64 + ntl*16 + c
    float xr[4][4][4];
    #pragma unroll
    for (int rg = 0; rg < 4; ++rg)
        #pragma unroll
        for (int reg = 0; reg < 4; ++reg) {
            int m = rg * 16 + 4 * q + reg;
            float mv = rowf[0][m], ev = rowf[1][m], lv = rowf[2][m], e2 = rowf[3][m];
            const float* srow = stab_table + rowi[0][m] * 256;
            const float* crow = cycle_table + rowi[1][m] * 256;
            #pragma unroll
            for (int ntl = 0; ntl < 4; ++ntl) {
                int n = w * 64 + ntl * 16 + c;
                xr[rg][ntl][reg] = mv * par[n] + ev * par[256 + n] + lv * par[512 + n]
                                 + e2 * par[768 + n] + par[1024 + n] + srow[n] + crow[n];
            }
        }
    __syncthreads();   // rowf/rowi reads done before red overlay writes

    auto layernorm_to_A = [&](const float* g, const float* be) {
        float s[4][4], s2[4][4];
        #pragma unroll
        for (int rg = 0; rg < 4; ++rg)
            #pragma unroll
            for (int reg = 0; reg < 4; ++reg) {
                float a = 0.f, b = 0.f;
                #pragma unroll
                for (int ntl = 0; ntl < 4; ++ntl) {
                    float v = xr[rg][ntl][reg];
                    a += v; b += v * v;
                }
                #pragma unroll
                for (int d = 1; d < 16; d <<= 1) {
                    a += __shfl_xor(a, d, 64);
                    b += __shfl_xor(b, d, 64);
                }
                s[rg][reg] = a; s2[rg][reg] = b;
            }
        if (c == 0) {
            #pragma unroll
            for (int rg = 0; rg < 4; ++rg)
                #pragma unroll
                for (int reg = 0; reg < 4; ++reg) {
                    int m = rg * 16 + 4 * q + reg;
                    red[0][w][m] = s[rg][reg];
                    red[1][w][m] = s2[rg][reg];
                }
        }
        __syncthreads();   // red visible; also all waves done reading Ahi
        if (tid < TT) {
            float a = red[0][0][tid] + red[0][1][tid] + red[0][2][tid] + red[0][3][tid];
            float b = red[1][0][tid] + red[1][1][tid] + red[1][2][tid] + red[1][3][tid];
            float mu = a * (1.0f / 256.0f);
            float var = b * (1.0f / 256.0f) - mu * mu;
            stat[0][tid] = mu;
            stat[1][tid] = rsqrtf(var + EPS);
        }
        __syncthreads();
        #pragma unroll
        for (int rg = 0; rg < 4; ++rg)
            #pragma unroll
            for (int reg = 0; reg < 4; ++reg) {
                int m = rg * 16 + 4 * q + reg;
                float mu = stat[0][m], rs = stat[1][m];
                #pragma unroll
                for (int ntl = 0; ntl < 4; ++ntl) {
                    int n = w * 64 + ntl * 16 + c;
                    Ahi[aidx(m, n)] = f2bf((xr[rg][ntl][reg] - mu) * rs * g[n] + be[n]);
                }
            }
        __syncthreads();
    };

    float4v acc[4][4];

    auto do_gemm = [&](int g) {
        const short* W = g_Wp + g * 65536;
        #pragma unroll
        for (int rg = 0; rg < 4; ++rg)
            #pragma unroll
            for (int ntl = 0; ntl < 4; ++ntl)
                acc[rg][ntl] = (float4v){0.f, 0.f, 0.f, 0.f};
        #pragma unroll
        for (int kb = 0; kb < 8; ++kb) {
            short8 ah[4], bh[4];
            #pragma unroll
            for (int rg = 0; rg < 4; ++rg)
                ah[rg] = *(const short8*)&Ahi[((rg * 8 + kb) * 64 + lane) * 8];
            #pragma unroll
            for (int ntl = 0; ntl < 4; ++ntl) {
                int nt = w * 4 + ntl;
                bh[ntl] = *(const short8*)&W[((nt * 8 + kb) * 64 + lane) * 8];
            }
            #pragma unroll
            for (int rg = 0; rg < 4; ++rg)
                #pragma unroll
                for (int ntl = 0; ntl < 4; ++ntl)
                    acc[rg][ntl] = __builtin_amdgcn_mfma_f32_16x16x32_bf16(
                        ah[rg], bh[ntl], acc[rg][ntl], 0, 0, 0);
        }
    };

    auto gelu_to_A = [&](const float* bias) {
        __syncthreads();   // all waves done reading previous A tile
        #pragma unroll
        for (int rg = 0; rg < 4; ++rg)
            #pragma unroll
            for (int ntl = 0; ntl < 4; ++ntl)
                #pragma unroll
                for (int reg = 0; reg < 4; ++reg) {
                    int m = rg * 16 + 4 * q + reg;
                    int n = w * 64 + ntl * 16 + c;
                    float v = acc[rg][ntl][reg] + bias[n];
                    Ahi[aidx(m, n)] = f2bf(gelu_erf(v));
                }
        __syncthreads();
    };

    // ---- res block 1 ----
    layernorm_to_A(par + 5 * 256, par + 6 * 256);
    do_gemm(0);
    gelu_to_A(par + 7 * 256);
    do_gemm(1);
    #pragma unroll
    for (int rg = 0; rg < 4; ++rg)
        #pragma unroll
        for (int ntl = 0; ntl < 4; ++ntl)
            #pragma unroll
            for (int reg = 0; reg < 4; ++reg) {
                int n = w * 64 + ntl * 16 + c;
                xr[rg][ntl][reg] += acc[rg][ntl][reg] + par[8 * 256 + n];
            }

    // ---- res block 2 ----
    layernorm_to_A(par + 9 * 256, par + 10 * 256);
    do_gemm(2);
    gelu_to_A(par + 11 * 256);
    do_gemm(3);

    // ---- epilogue: out = x + C4 + b22 ----
    #pragma unroll
    for (int rg = 0; rg < 4; ++rg)
        #pragma unroll
        for (int ntl = 0; ntl < 4; ++ntl)
            #pragma unroll
            for (int reg = 0; reg < 4; ++reg) {
                int m = rg * 16 + 4 * q + reg;
                int n = w * 64 + ntl * 16 + c;
                out[(size_t)(R0 + m) * 256 + n] =
                    xr[rg][ntl][reg] + acc[rg][ntl][reg] + par[12 * 256 + n];
            }
}

extern "C" void kernel_launch(void* const* d_in, const int* in_sizes, int n_in,
                              void* d_out, int out_size, void* d_ws, size_t ws_size,
                              hipStream_t stream) {
    pack_w<<<1024, 256, 0, stream>>>(
        (const float*)d_in[18], (const float*)d_in[20],
        (const float*)d_in[24], (const float*)d_in[26]);
    fused_kernel<<<NTOK / TT, 256, 0, stream>>>(
        (const float*)d_in[0], (const float*)d_in[1],
        (const float*)d_in[2], (const float*)d_in[3],
        (const int*)d_in[4], (const int*)d_in[5],
        (const float*)d_in[6], (const float*)d_in[8],
        (const float*)d_in[10], (const float*)d_in[12],
        (const float*)d_in[7], (const float*)d_in[9],
        (const float*)d_in[11], (const float*)d_in[13],
        (const float*)d_in[14], (const float*)d_in[15],
        (const float*)d_in[16], (const float*)d_in[17],
        (const float*)d_in[19], (const float*)d_in[21],
        (const float*)d_in[22], (const float*)d_in[23],
        (const float*)d_in[25], (const float*)d_in[27],
        (float*)d_out);
}